// Round 11
// baseline (75.068 us; speedup 1.0000x reference)
//
#include <hip/hip_runtime.h>

#define TB 256   // T (sequence length)
#define CC 64    // C (embed)
#define HH 64    // H (head size)

typedef __attribute__((ext_vector_type(8))) short short8;   // 8 bf16 (4 VGPRs)
typedef __attribute__((ext_vector_type(4))) float f32x4;    // MFMA C/D frag

#define MFMA16(a, b, c) __builtin_amdgcn_mfma_f32_16x16x32_bf16((a), (b), (c), 0, 0, 0)

// bf16 convert, round-half-up: 2 VALU/elem; tie bias ~2^-17 relative (absmax-safe, proven R3-R6).
__device__ __forceinline__ unsigned short f2bf(float f) {
    union { float f; unsigned u; } v; v.f = f;
    return (unsigned short)((v.u + 0x8000u) >> 16);
}

__device__ __forceinline__ short8 pack8(f32x4 a, f32x4 b) {
    short8 r;
    r[0] = (short)f2bf(a[0]); r[1] = (short)f2bf(a[1]);
    r[2] = (short)f2bf(a[2]); r[3] = (short)f2bf(a[3]);
    r[4] = (short)f2bf(b[0]); r[5] = (short)f2bf(b[1]);
    r[6] = (short)f2bf(b[2]); r[7] = (short)f2bf(b[3]);
    return r;
}

__device__ __forceinline__ unsigned long long pack4(f32x4 a) {
    return  (unsigned long long)f2bf(a[0])
         | ((unsigned long long)f2bf(a[1]) << 16)
         | ((unsigned long long)f2bf(a[2]) << 32)
         | ((unsigned long long)f2bf(a[3]) << 48);
}

// Pre-kernel: W -> MFMA-ready bf16 fragments (proven R4). Layout byte-identical to wb frags.
__global__ __launch_bounds__(512, 1)
void pack_w(const float* __restrict__ Wq, const float* __restrict__ Wk,
            const float* __restrict__ Wv, short8* __restrict__ wf) {
    const int tid  = threadIdx.x;
    const int lane = tid & 63;
    const int lr   = lane & 15;
    const int lg   = lane >> 4;
    const int idx  = tid >> 6;        // 0..7
    const int t    = idx >> 1;
    const int kk   = idx & 1;
    const float* Ws[3] = { Wq, Wk, Wv };
#pragma unroll
    for (int m = 0; m < 3; ++m) {
        const f32x4* p4 = (const f32x4*)(Ws[m] + (16 * t + lr) * CC + kk * 32 + lg * 8);
        wf[((m * 4 + t) * 2 + kk) * 64 + lane] = pack8(p4[0], p4[1]);
    }
}

// EXACT R6 kernel (proven: 71.8us, absmax 0.0234) + T5 s_setprio around MFMA clusters.
// The R7-R9 shared-operand transform is abandoned: three inspection-clean failures with
// schedule-dependent signatures = compiler/exec-mask hazard in that pattern.
template<bool WSF>
__global__ __launch_bounds__(512, 4)
void attn_fused(const float* __restrict__ x, const float* __restrict__ Wq,
                const float* __restrict__ Wk, const float* __restrict__ Wv,
                const short8* __restrict__ wf, float* __restrict__ out)
{
    // 64 KiB shared, phase-aliased: Phase B/C: kf(32K)+vq(32K); epilogue: fp32 stage[256][64]
    __shared__ __align__(16) char smem[65536];
    short8* kf_lds = (short8*)smem;                                   // [16][2][4][16]
    unsigned long long* vq_lds = (unsigned long long*)(smem + 32768); // [4][64][16]
    float* stage = (float*)smem;

    const int b    = blockIdx.x;
    const int tid  = threadIdx.x;
    const int wave = tid >> 6;
    const int lane = tid & 63;
    const int lr   = lane & 15;
    const int lg   = lane >> 4;
    const int xsw  = (lr & 7) << 1;   // vq swizzle (even -> preserves b128 pairing)

    const int sA = wave;              // light strip
    const int sB = 15 - wave;         // heavy strip
    const int ntA = sA + 1;
    const int ntB = sB + 1;

    // ---------- Phase A: x fragments for both strips ----------
    short8 xa[2][2];
#pragma unroll
    for (int sp = 0; sp < 2; ++sp) {
        const int s = sp ? sB : sA;
        const float* xr = x + ((size_t)b * TB + s * 16 + lr) * CC;
#pragma unroll
        for (int kk = 0; kk < 2; ++kk) {
            const f32x4* p4 = (const f32x4*)(xr + kk * 32 + lg * 8);
            xa[sp][kk] = pack8(p4[0], p4[1]);
        }
    }

    // ---------- Phase B: q^T,k^T = W@x^T (lane=pos); v = x@W^T (lane=h) — proven R4 ----------
    short8 qfA[2], qfB[2];
    const float* Ws[3] = { Wq, Wk, Wv };
#pragma unroll
    for (int m = 0; m < 3; ++m) {
        short8 wb[4][2];
        if constexpr (WSF) {
#pragma unroll
            for (int t = 0; t < 4; ++t)
#pragma unroll
                for (int kk = 0; kk < 2; ++kk)
                    wb[t][kk] = wf[((m * 4 + t) * 2 + kk) * 64 + lane];
        } else {
#pragma unroll
            for (int t = 0; t < 4; ++t)
#pragma unroll
                for (int kk = 0; kk < 2; ++kk) {
                    const f32x4* p4 = (const f32x4*)(Ws[m] + (16 * t + lr) * CC + kk * 32 + lg * 8);
                    wb[t][kk] = pack8(p4[0], p4[1]);
                }
        }
#pragma unroll
        for (int sp = 0; sp < 2; ++sp) {
            const int s = sp ? sB : sA;
            f32x4 acc[4];
#pragma unroll
            for (int t = 0; t < 4; ++t) acc[t] = (f32x4){0.f, 0.f, 0.f, 0.f};
            __builtin_amdgcn_s_setprio(1);
#pragma unroll
            for (int kk = 0; kk < 2; ++kk)
#pragma unroll
                for (int t = 0; t < 4; ++t)
                    acc[t] = (m < 2) ? MFMA16(wb[t][kk], xa[sp][kk], acc[t])   // W in A slot -> transposed D
                                     : MFMA16(xa[sp][kk], wb[t][kk], acc[t]);  // x in A slot -> standard D
            __builtin_amdgcn_s_setprio(0);

            if (m == 0) {
#pragma unroll
                for (int kk = 0; kk < 2; ++kk) {
                    short8 q = pack8(acc[2 * kk], acc[2 * kk + 1]);
                    if (sp) qfB[kk] = q; else qfA[kk] = q;
                }
            } else if (m == 1) {
#pragma unroll
                for (int kk = 0; kk < 2; ++kk)
                    kf_lds[((s * 2 + kk) * 4 + lg) * 16 + lr] = pack8(acc[2 * kk], acc[2 * kk + 1]);
            } else {
#pragma unroll
                for (int t = 0; t < 4; ++t)
                    vq_lds[(lg * 64 + 16 * t + lr) * 16 + (s ^ xsw)] = pack4(acc[t]);
            }
        }
    }
    __syncthreads();

    // ---------- Phase C: streaming causal attention, dual-strip interleaved (R6 exact) ----------
    const float kexp = 0.125f * 1.44269504088896f;   // scale * log2(e)
    f32x4 oA[4], oB[4];
#pragma unroll
    for (int t = 0; t < 4; ++t) {
        oA[t] = (f32x4){0.f, 0.f, 0.f, 0.f};
        oB[t] = (f32x4){0.f, 0.f, 0.f, 0.f};
    }
    f32x4 smA = (f32x4){0.f, 0.f, 0.f, 0.f};
    f32x4 smB = (f32x4){0.f, 0.f, 0.f, 0.f};

#pragma unroll
    for (int kt = 0; kt < 8; ++kt) {
        // ---- strip A tile-pair kt (wave-uniform guard) ----
        if (2 * kt < ntA) {
            const int j0 = 2 * kt, j1 = 2 * kt + 1;
            f32x4 p0 = (f32x4){0.f, 0.f, 0.f, 0.f};
            f32x4 p1 = (f32x4){0.f, 0.f, 0.f, 0.f};
            __builtin_amdgcn_s_setprio(1);
#pragma unroll
            for (int kk = 0; kk < 2; ++kk)
                p0 = MFMA16(kf_lds[((j0 * 2 + kk) * 4 + lg) * 16 + lr], qfA[kk], p0);
            const bool h1 = (j1 < ntA);
            if (h1) {
#pragma unroll
                for (int kk = 0; kk < 2; ++kk)
                    p1 = MFMA16(kf_lds[((j1 * 2 + kk) * 4 + lg) * 16 + lr], qfA[kk], p1);
            }
            __builtin_amdgcn_s_setprio(0);
#pragma unroll
            for (int e = 0; e < 4; ++e) p0[e] = __builtin_amdgcn_exp2f(p0[e] * kexp);
            if (j0 == sA) {
#pragma unroll
                for (int e = 0; e < 4; ++e) p0[e] = (4 * lg + e > lr) ? 0.f : p0[e];
            }
            if (h1) {
#pragma unroll
                for (int e = 0; e < 4; ++e) p1[e] = __builtin_amdgcn_exp2f(p1[e] * kexp);
                if (j1 == sA) {
#pragma unroll
                    for (int e = 0; e < 4; ++e) p1[e] = (4 * lg + e > lr) ? 0.f : p1[e];
                }
            }
#pragma unroll
            for (int e = 0; e < 4; ++e) smA[e] += p0[e] + p1[e];
            short8 pa = pack8(p0, p1);
            __builtin_amdgcn_s_setprio(1);
#pragma unroll
            for (int t = 0; t < 4; ++t) {
                short8 vb = *(const short8*)&vq_lds[(lg * 64 + 16 * t + lr) * 16 + ((2 * kt) ^ xsw)];
                oA[t] = MFMA16(pa, vb, oA[t]);
            }
            __builtin_amdgcn_s_setprio(0);
        }
        // ---- strip B tile-pair kt ----
        if (2 * kt < ntB) {
            const int j0 = 2 * kt, j1 = 2 * kt + 1;
            f32x4 p0 = (f32x4){0.f, 0.f, 0.f, 0.f};
            f32x4 p1 = (f32x4){0.f, 0.f, 0.f, 0.f};
            __builtin_amdgcn_s_setprio(1);
#pragma unroll
            for (int kk = 0; kk < 2; ++kk)
                p0 = MFMA16(kf_lds[((j0 * 2 + kk) * 4 + lg) * 16 + lr], qfB[kk], p0);
            const bool h1 = (j1 < ntB);
            if (h1) {
#pragma unroll
                for (int kk = 0; kk < 2; ++kk)
                    p1 = MFMA16(kf_lds[((j1 * 2 + kk) * 4 + lg) * 16 + lr], qfB[kk], p1);
            }
            __builtin_amdgcn_s_setprio(0);
#pragma unroll
            for (int e = 0; e < 4; ++e) p0[e] = __builtin_amdgcn_exp2f(p0[e] * kexp);
            if (j0 == sB) {
#pragma unroll
                for (int e = 0; e < 4; ++e) p0[e] = (4 * lg + e > lr) ? 0.f : p0[e];
            }
            if (h1) {
#pragma unroll
                for (int e = 0; e < 4; ++e) p1[e] = __builtin_amdgcn_exp2f(p1[e] * kexp);
                if (j1 == sB) {
#pragma unroll
                    for (int e = 0; e < 4; ++e) p1[e] = (4 * lg + e > lr) ? 0.f : p1[e];
                }
            }
#pragma unroll
            for (int e = 0; e < 4; ++e) smB[e] += p0[e] + p1[e];
            short8 pa = pack8(p0, p1);
            __builtin_amdgcn_s_setprio(1);
#pragma unroll
            for (int t = 0; t < 4; ++t) {
                short8 vb = *(const short8*)&vq_lds[(lg * 64 + 16 * t + lr) * 16 + ((2 * kt) ^ xsw)];
                oB[t] = MFMA16(pa, vb, oB[t]);
            }
            __builtin_amdgcn_s_setprio(0);
        }
    }
    float fA = (smA[0] + smA[1]) + (smA[2] + smA[3]);
    fA += __shfl_xor(fA, 16);
    fA += __shfl_xor(fA, 32);
    float fB = (smB[0] + smB[1]) + (smB[2] + smB[3]);
    fB += __shfl_xor(fB, 16);
    fB += __shfl_xor(fB, 32);
    const float rvA = __builtin_amdgcn_rcpf(fA);
    const float rvB = __builtin_amdgcn_rcpf(fB);

    // ---------- Epilogue: LDS restage (kf/vq dead) -> coalesced dwordx4 stores — proven R4 ----------
    __syncthreads();
#pragma unroll
    for (int sp = 0; sp < 2; ++sp) {
        const int s = sp ? sB : sA;
        const float rv = sp ? rvB : rvA;
        float dn[4];
#pragma unroll
        for (int reg = 0; reg < 4; ++reg) dn[reg] = __shfl(rv, 4 * lg + reg);
#pragma unroll
        for (int t = 0; t < 4; ++t)
#pragma unroll
            for (int reg = 0; reg < 4; ++reg) {
                const int row = 4 * lg + reg;                    // query row within strip
                const int col = (16 * t + lr) ^ (lg << 4);       // XOR key = row>>2 = lg
                const f32x4 o = sp ? oB[t] : oA[t];
                stage[(s * 16 + row) * 64 + col] = o[reg] * dn[reg];
            }
    }
    // own-wave data only: compiler inserts the lgkmcnt wait for the ds_write->ds_read dep
#pragma unroll
    for (int sp = 0; sp < 2; ++sp) {
        const int s = sp ? sB : sA;
#pragma unroll
        for (int i = 0; i < 4; ++i) {
            const int row = 4 * i + lg;
            const int col = (4 * lr) ^ (i << 4);                 // XOR key = row>>2 = i
            f32x4 vv = *(const f32x4*)&stage[(s * 16 + row) * 64 + col];
            *(f32x4*)&out[((size_t)b * TB + 16 * s + row) * HH + 4 * lr] = vv;
        }
    }
}

extern "C" void kernel_launch(void* const* d_in, const int* in_sizes, int n_in,
                              void* d_out, int out_size, void* d_ws, size_t ws_size,
                              hipStream_t stream) {
    const float* x  = (const float*)d_in[0];
    const float* Wq = (const float*)d_in[1];
    const float* Wk = (const float*)d_in[2];
    const float* Wv = (const float*)d_in[3];
    float* out = (float*)d_out;
    const int Bn = in_sizes[0] / (TB * CC);   // 2048
    if (ws_size >= 3 * 4 * 2 * 64 * sizeof(short8)) {
        short8* wf = (short8*)d_ws;
        pack_w<<<1, 512, 0, stream>>>(Wq, Wk, Wv, wf);
        attn_fused<true><<<Bn, 512, 0, stream>>>(x, Wq, Wk, Wv, wf, out);
    } else {
        attn_fused<false><<<Bn, 512, 0, stream>>>(x, Wq, Wk, Wv, nullptr, out);
    }
}

// Round 12
// 71.889 us; speedup vs baseline: 1.0442x; 1.0442x over previous
//
#include <hip/hip_runtime.h>

#define TB 256   // T (sequence length)
#define CC 64    // C (embed)
#define HH 64    // H (head size)

typedef __attribute__((ext_vector_type(8))) short short8;   // 8 bf16 (4 VGPRs)
typedef __attribute__((ext_vector_type(4))) float f32x4;    // MFMA C/D frag

#define MFMA16(a, b, c) __builtin_amdgcn_mfma_f32_16x16x32_bf16((a), (b), (c), 0, 0, 0)

// bf16 convert, round-half-up: 2 VALU/elem; tie bias ~2^-17 relative (absmax-safe, proven R3-R6).
__device__ __forceinline__ unsigned short f2bf(float f) {
    union { float f; unsigned u; } v; v.f = f;
    return (unsigned short)((v.u + 0x8000u) >> 16);
}

__device__ __forceinline__ short8 pack8(f32x4 a, f32x4 b) {
    short8 r;
    r[0] = (short)f2bf(a[0]); r[1] = (short)f2bf(a[1]);
    r[2] = (short)f2bf(a[2]); r[3] = (short)f2bf(a[3]);
    r[4] = (short)f2bf(b[0]); r[5] = (short)f2bf(b[1]);
    r[6] = (short)f2bf(b[2]); r[7] = (short)f2bf(b[3]);
    return r;
}

__device__ __forceinline__ unsigned long long pack4(f32x4 a) {
    return  (unsigned long long)f2bf(a[0])
         | ((unsigned long long)f2bf(a[1]) << 16)
         | ((unsigned long long)f2bf(a[2]) << 32)
         | ((unsigned long long)f2bf(a[3]) << 48);
}

// Pre-kernel: W -> MFMA-ready bf16 fragments (proven R4). Layout byte-identical to wb frags.
__global__ __launch_bounds__(512, 1)
void pack_w(const float* __restrict__ Wq, const float* __restrict__ Wk,
            const float* __restrict__ Wv, short8* __restrict__ wf) {
    const int tid  = threadIdx.x;
    const int lane = tid & 63;
    const int lr   = lane & 15;
    const int lg   = lane >> 4;
    const int idx  = tid >> 6;        // 0..7
    const int t    = idx >> 1;
    const int kk   = idx & 1;
    const float* Ws[3] = { Wq, Wk, Wv };
#pragma unroll
    for (int m = 0; m < 3; ++m) {
        const f32x4* p4 = (const f32x4*)(Ws[m] + (16 * t + lr) * CC + kk * 32 + lg * 8);
        wf[((m * 4 + t) * 2 + kk) * 64 + lane] = pack8(p4[0], p4[1]);
    }
}

// R6 shell (proven 71.8us). Phase C: operand loads hoisted FULLY OUTSIDE the strip
// guards (unguarded-def -> guarded-use, the pattern R6's qfA/qfB already prove safe;
// R7-R9's guarded-def -> differently-guarded-use is abandoned). One shared load set
// per kt serves both strips. No setprio (R10: -4.6%).
template<bool WSF>
__global__ __launch_bounds__(512, 4)
void attn_fused(const float* __restrict__ x, const float* __restrict__ Wq,
                const float* __restrict__ Wk, const float* __restrict__ Wv,
                const short8* __restrict__ wf, float* __restrict__ out)
{
    // 64 KiB shared, phase-aliased: Phase B/C: kf(32K)+vq(32K); epilogue: fp32 stage[256][64]
    __shared__ __align__(16) char smem[65536];
    short8* kf_lds = (short8*)smem;                                   // [16][2][4][16]
    unsigned long long* vq_lds = (unsigned long long*)(smem + 32768); // [4][64][16]
    float* stage = (float*)smem;

    const int b    = blockIdx.x;
    const int tid  = threadIdx.x;
    const int wave = tid >> 6;
    const int lane = tid & 63;
    const int lr   = lane & 15;
    const int lg   = lane >> 4;
    const int xsw  = (lr & 7) << 1;   // vq swizzle (even -> preserves b128 pairing)

    const int sA = wave;              // light strip (ntA <= 8)
    const int sB = 15 - wave;         // heavy strip (ntB >= 9)
    const int ntA = sA + 1;
    const int ntB = sB + 1;

    // ---------- Phase A: x fragments for both strips ----------
    short8 xa[2][2];
#pragma unroll
    for (int sp = 0; sp < 2; ++sp) {
        const int s = sp ? sB : sA;
        const float* xr = x + ((size_t)b * TB + s * 16 + lr) * CC;
#pragma unroll
        for (int kk = 0; kk < 2; ++kk) {
            const f32x4* p4 = (const f32x4*)(xr + kk * 32 + lg * 8);
            xa[sp][kk] = pack8(p4[0], p4[1]);
        }
    }

    // ---------- Phase B: q^T,k^T = W@x^T (lane=pos); v = x@W^T (lane=h) — proven R4 ----------
    short8 qfA[2], qfB[2];
    const float* Ws[3] = { Wq, Wk, Wv };
#pragma unroll
    for (int m = 0; m < 3; ++m) {
        short8 wb[4][2];
        if constexpr (WSF) {
#pragma unroll
            for (int t = 0; t < 4; ++t)
#pragma unroll
                for (int kk = 0; kk < 2; ++kk)
                    wb[t][kk] = wf[((m * 4 + t) * 2 + kk) * 64 + lane];
        } else {
#pragma unroll
            for (int t = 0; t < 4; ++t)
#pragma unroll
                for (int kk = 0; kk < 2; ++kk) {
                    const f32x4* p4 = (const f32x4*)(Ws[m] + (16 * t + lr) * CC + kk * 32 + lg * 8);
                    wb[t][kk] = pack8(p4[0], p4[1]);
                }
        }
#pragma unroll
        for (int sp = 0; sp < 2; ++sp) {
            const int s = sp ? sB : sA;
            f32x4 acc[4];
#pragma unroll
            for (int t = 0; t < 4; ++t) acc[t] = (f32x4){0.f, 0.f, 0.f, 0.f};
#pragma unroll
            for (int kk = 0; kk < 2; ++kk)
#pragma unroll
                for (int t = 0; t < 4; ++t)
                    acc[t] = (m < 2) ? MFMA16(wb[t][kk], xa[sp][kk], acc[t])   // W in A slot -> transposed D
                                     : MFMA16(xa[sp][kk], wb[t][kk], acc[t]);  // x in A slot -> standard D

            if (m == 0) {
#pragma unroll
                for (int kk = 0; kk < 2; ++kk) {
                    short8 q = pack8(acc[2 * kk], acc[2 * kk + 1]);
                    if (sp) qfB[kk] = q; else qfA[kk] = q;
                }
            } else if (m == 1) {
#pragma unroll
                for (int kk = 0; kk < 2; ++kk)
                    kf_lds[((s * 2 + kk) * 4 + lg) * 16 + lr] = pack8(acc[2 * kk], acc[2 * kk + 1]);
            } else {
#pragma unroll
                for (int t = 0; t < 4; ++t)
                    vq_lds[(lg * 64 + 16 * t + lr) * 16 + (s ^ xsw)] = pack4(acc[t]);
            }
        }
    }
    __syncthreads();

    // ---------- Phase C: streaming causal attention; loads hoisted & shared ----------
    const float kexp = 0.125f * 1.44269504088896f;   // scale * log2(e)
    f32x4 oA[4], oB[4];
#pragma unroll
    for (int t = 0; t < 4; ++t) {
        oA[t] = (f32x4){0.f, 0.f, 0.f, 0.f};
        oB[t] = (f32x4){0.f, 0.f, 0.f, 0.f};
    }
    f32x4 smA = (f32x4){0.f, 0.f, 0.f, 0.f};
    f32x4 smB = (f32x4){0.f, 0.f, 0.f, 0.f};

#pragma unroll
    for (int kt = 0; kt < 8; ++kt) {
        const int j0 = 2 * kt, j1 = 2 * kt + 1;

        // ---- UNGUARDED shared loads (always in-bounds: kf has 16 tiles, vb slots even<=14) ----
        const short8 kf0a = kf_lds[((j0 * 2 + 0) * 4 + lg) * 16 + lr];
        const short8 kf0b = kf_lds[((j0 * 2 + 1) * 4 + lg) * 16 + lr];
        const short8 kf1a = kf_lds[((j1 * 2 + 0) * 4 + lg) * 16 + lr];
        const short8 kf1b = kf_lds[((j1 * 2 + 1) * 4 + lg) * 16 + lr];
        const short8 vb0 = *(const short8*)&vq_lds[(lg * 64 +  0 + lr) * 16 + (j0 ^ xsw)];
        const short8 vb1 = *(const short8*)&vq_lds[(lg * 64 + 16 + lr) * 16 + (j0 ^ xsw)];
        const short8 vb2 = *(const short8*)&vq_lds[(lg * 64 + 32 + lr) * 16 + (j0 ^ xsw)];
        const short8 vb3 = *(const short8*)&vq_lds[(lg * 64 + 48 + lr) * 16 + (j0 ^ xsw)];

        // ---- strip A tile-pair kt (verbatim R6 block; LDS reads renamed) ----
        if (2 * kt < ntA) {
            f32x4 p0 = (f32x4){0.f, 0.f, 0.f, 0.f};
            f32x4 p1 = (f32x4){0.f, 0.f, 0.f, 0.f};
            p0 = MFMA16(kf0a, qfA[0], p0);
            p0 = MFMA16(kf0b, qfA[1], p0);
            const bool h1 = (j1 < ntA);
            if (h1) {
                p1 = MFMA16(kf1a, qfA[0], p1);
                p1 = MFMA16(kf1b, qfA[1], p1);
            }
#pragma unroll
            for (int e = 0; e < 4; ++e) p0[e] = __builtin_amdgcn_exp2f(p0[e] * kexp);
            if (j0 == sA) {
#pragma unroll
                for (int e = 0; e < 4; ++e) p0[e] = (4 * lg + e > lr) ? 0.f : p0[e];
            }
            if (h1) {
#pragma unroll
                for (int e = 0; e < 4; ++e) p1[e] = __builtin_amdgcn_exp2f(p1[e] * kexp);
                if (j1 == sA) {
#pragma unroll
                    for (int e = 0; e < 4; ++e) p1[e] = (4 * lg + e > lr) ? 0.f : p1[e];
                }
            }
#pragma unroll
            for (int e = 0; e < 4; ++e) smA[e] += p0[e] + p1[e];
            short8 pa = pack8(p0, p1);
            oA[0] = MFMA16(pa, vb0, oA[0]);
            oA[1] = MFMA16(pa, vb1, oA[1]);
            oA[2] = MFMA16(pa, vb2, oA[2]);
            oA[3] = MFMA16(pa, vb3, oA[3]);
        }

        // ---- strip B tile-pair kt (verbatim R6 block; LDS reads renamed) ----
        if (2 * kt < ntB) {
            f32x4 p0 = (f32x4){0.f, 0.f, 0.f, 0.f};
            f32x4 p1 = (f32x4){0.f, 0.f, 0.f, 0.f};
            p0 = MFMA16(kf0a, qfB[0], p0);
            p0 = MFMA16(kf0b, qfB[1], p0);
            const bool h1 = (j1 < ntB);
            if (h1) {
                p1 = MFMA16(kf1a, qfB[0], p1);
                p1 = MFMA16(kf1b, qfB[1], p1);
            }
#pragma unroll
            for (int e = 0; e < 4; ++e) p0[e] = __builtin_amdgcn_exp2f(p0[e] * kexp);
            if (j0 == sB) {
#pragma unroll
                for (int e = 0; e < 4; ++e) p0[e] = (4 * lg + e > lr) ? 0.f : p0[e];
            }
            if (h1) {
#pragma unroll
                for (int e = 0; e < 4; ++e) p1[e] = __builtin_amdgcn_exp2f(p1[e] * kexp);
                if (j1 == sB) {
#pragma unroll
                    for (int e = 0; e < 4; ++e) p1[e] = (4 * lg + e > lr) ? 0.f : p1[e];
                }
            }
#pragma unroll
            for (int e = 0; e < 4; ++e) smB[e] += p0[e] + p1[e];
            short8 pa = pack8(p0, p1);
            oB[0] = MFMA16(pa, vb0, oB[0]);
            oB[1] = MFMA16(pa, vb1, oB[1]);
            oB[2] = MFMA16(pa, vb2, oB[2]);
            oB[3] = MFMA16(pa, vb3, oB[3]);
        }
    }
    float fA = (smA[0] + smA[1]) + (smA[2] + smA[3]);
    fA += __shfl_xor(fA, 16);
    fA += __shfl_xor(fA, 32);
    float fB = (smB[0] + smB[1]) + (smB[2] + smB[3]);
    fB += __shfl_xor(fB, 16);
    fB += __shfl_xor(fB, 32);
    const float rvA = __builtin_amdgcn_rcpf(fA);
    const float rvB = __builtin_amdgcn_rcpf(fB);

    // ---------- Epilogue: LDS restage (kf/vq dead) -> coalesced dwordx4 stores — proven R4 ----------
    __syncthreads();
#pragma unroll
    for (int sp = 0; sp < 2; ++sp) {
        const int s = sp ? sB : sA;
        const float rv = sp ? rvB : rvA;
        float dn[4];
#pragma unroll
        for (int reg = 0; reg < 4; ++reg) dn[reg] = __shfl(rv, 4 * lg + reg);
#pragma unroll
        for (int t = 0; t < 4; ++t)
#pragma unroll
            for (int reg = 0; reg < 4; ++reg) {
                const int row = 4 * lg + reg;                    // query row within strip
                const int col = (16 * t + lr) ^ (lg << 4);       // XOR key = row>>2 = lg
                const f32x4 o = sp ? oB[t] : oA[t];
                stage[(s * 16 + row) * 64 + col] = o[reg] * dn[reg];
            }
    }
    // own-wave data only: compiler inserts the lgkmcnt wait for the ds_write->ds_read dep
#pragma unroll
    for (int sp = 0; sp < 2; ++sp) {
        const int s = sp ? sB : sA;
#pragma unroll
        for (int i = 0; i < 4; ++i) {
            const int row = 4 * i + lg;
            const int col = (4 * lr) ^ (i << 4);                 // XOR key = row>>2 = i
            f32x4 vv = *(const f32x4*)&stage[(s * 16 + row) * 64 + col];
            *(f32x4*)&out[((size_t)b * TB + 16 * s + row) * HH + 4 * lr] = vv;
        }
    }
}

extern "C" void kernel_launch(void* const* d_in, const int* in_sizes, int n_in,
                              void* d_out, int out_size, void* d_ws, size_t ws_size,
                              hipStream_t stream) {
    const float* x  = (const float*)d_in[0];
    const float* Wq = (const float*)d_in[1];
    const float* Wk = (const float*)d_in[2];
    const float* Wv = (const float*)d_in[3];
    float* out = (float*)d_out;
    const int Bn = in_sizes[0] / (TB * CC);   // 2048
    if (ws_size >= 3 * 4 * 2 * 64 * sizeof(short8)) {
        short8* wf = (short8*)d_ws;
        pack_w<<<1, 512, 0, stream>>>(Wq, Wk, Wv, wf);
        attn_fused<true><<<Bn, 512, 0, stream>>>(x, Wq, Wk, Wv, wf, out);
    } else {
        attn_fused<false><<<Bn, 512, 0, stream>>>(x, Wq, Wk, Wv, nullptr, out);
    }
}

// Round 13
// 66.479 us; speedup vs baseline: 1.1292x; 1.0814x over previous
//
#include <hip/hip_runtime.h>
#include <hip/hip_bf16.h>

#define TB 256   // T (sequence length)
#define CC 64    // C (embed)
#define HH 64    // H (head size)

typedef __attribute__((ext_vector_type(8))) short short8;   // 8 bf16 (4 VGPRs)
typedef __attribute__((ext_vector_type(4))) float f32x4;    // MFMA C/D frag

#define MFMA16(a, b, c) __builtin_amdgcn_mfma_f32_16x16x32_bf16((a), (b), (c), 0, 0, 0)

// Packed f32->bf16 pair via HIP intrinsic (lowers to v_cvt_pk_bf16_f32; m240: use
// casts/intrinsics, NOT inline asm). RNE rounding.
__device__ __forceinline__ unsigned cvt2(float lo, float hi) {
    union { __hip_bfloat162 h2; unsigned u; } cv;
    cv.h2 = __float22bfloat162_rn(make_float2(lo, hi));
    return cv.u;
}

union S8U { short8 s8; unsigned u32[4]; unsigned long long u64[2]; };

__device__ __forceinline__ short8 pack8(f32x4 a, f32x4 b) {
    S8U r;
    r.u32[0] = cvt2(a[0], a[1]);
    r.u32[1] = cvt2(a[2], a[3]);
    r.u32[2] = cvt2(b[0], b[1]);
    r.u32[3] = cvt2(b[2], b[3]);
    return r.s8;
}

__device__ __forceinline__ unsigned long long pack4(f32x4 a) {
    S8U r;
    r.u32[0] = cvt2(a[0], a[1]);
    r.u32[1] = cvt2(a[2], a[3]);
    return r.u64[0];
}

// Pre-kernel: W -> MFMA-ready bf16 fragments (proven R4). Layout byte-identical to wb frags.
__global__ __launch_bounds__(512, 1)
void pack_w(const float* __restrict__ Wq, const float* __restrict__ Wk,
            const float* __restrict__ Wv, short8* __restrict__ wf) {
    const int tid  = threadIdx.x;
    const int lane = tid & 63;
    const int lr   = lane & 15;
    const int lg   = lane >> 4;
    const int idx  = tid >> 6;        // 0..7
    const int t    = idx >> 1;
    const int kk   = idx & 1;
    const float* Ws[3] = { Wq, Wk, Wv };
#pragma unroll
    for (int m = 0; m < 3; ++m) {
        const f32x4* p4 = (const f32x4*)(Ws[m] + (16 * t + lr) * CC + kk * 32 + lg * 8);
        wf[((m * 4 + t) * 2 + kk) * 64 + lane] = pack8(p4[0], p4[1]);
    }
}

// R11 shell (proven 71.9us) with VALU-lean conversions:
//  - all f32->bf16 via v_cvt_pk path (1 VALU / 2 elems vs ~7 for bit-twiddle)
//  - scale*log2(e) folded into Q fragments at Phase-B pack (exp2 applied raw in Phase C)
template<bool WSF>
__global__ __launch_bounds__(512, 4)
void attn_fused(const float* __restrict__ x, const float* __restrict__ Wq,
                const float* __restrict__ Wk, const float* __restrict__ Wv,
                const short8* __restrict__ wf, float* __restrict__ out)
{
    // 64 KiB shared, phase-aliased: Phase B/C: kf(32K)+vq(32K); epilogue: fp32 stage[256][64]
    __shared__ __align__(16) char smem[65536];
    short8* kf_lds = (short8*)smem;                                   // [16][2][4][16]
    unsigned long long* vq_lds = (unsigned long long*)(smem + 32768); // [4][64][16]
    float* stage = (float*)smem;

    const int b    = blockIdx.x;
    const int tid  = threadIdx.x;
    const int wave = tid >> 6;
    const int lane = tid & 63;
    const int lr   = lane & 15;
    const int lg   = lane >> 4;
    const int xsw  = (lr & 7) << 1;   // vq swizzle (even -> preserves b128 pairing)

    const int sA = wave;              // light strip (ntA <= 8)
    const int sB = 15 - wave;         // heavy strip (ntB >= 9)
    const int ntA = sA + 1;
    const int ntB = sB + 1;

    const float kexp = 0.125f * 1.44269504088896f;   // scale * log2(e), folded into Q

    // ---------- Phase A: x fragments for both strips ----------
    short8 xa[2][2];
#pragma unroll
    for (int sp = 0; sp < 2; ++sp) {
        const int s = sp ? sB : sA;
        const float* xr = x + ((size_t)b * TB + s * 16 + lr) * CC;
#pragma unroll
        for (int kk = 0; kk < 2; ++kk) {
            const f32x4* p4 = (const f32x4*)(xr + kk * 32 + lg * 8);
            xa[sp][kk] = pack8(p4[0], p4[1]);
        }
    }

    // ---------- Phase B: q^T,k^T = W@x^T (lane=pos); v = x@W^T (lane=h) — proven R4 ----------
    short8 qfA[2], qfB[2];
    const float* Ws[3] = { Wq, Wk, Wv };
#pragma unroll
    for (int m = 0; m < 3; ++m) {
        short8 wb[4][2];
        if constexpr (WSF) {
#pragma unroll
            for (int t = 0; t < 4; ++t)
#pragma unroll
                for (int kk = 0; kk < 2; ++kk)
                    wb[t][kk] = wf[((m * 4 + t) * 2 + kk) * 64 + lane];
        } else {
#pragma unroll
            for (int t = 0; t < 4; ++t)
#pragma unroll
                for (int kk = 0; kk < 2; ++kk) {
                    const f32x4* p4 = (const f32x4*)(Ws[m] + (16 * t + lr) * CC + kk * 32 + lg * 8);
                    wb[t][kk] = pack8(p4[0], p4[1]);
                }
        }
#pragma unroll
        for (int sp = 0; sp < 2; ++sp) {
            const int s = sp ? sB : sA;
            f32x4 acc[4];
#pragma unroll
            for (int t = 0; t < 4; ++t) acc[t] = (f32x4){0.f, 0.f, 0.f, 0.f};
#pragma unroll
            for (int kk = 0; kk < 2; ++kk)
#pragma unroll
                for (int t = 0; t < 4; ++t)
                    acc[t] = (m < 2) ? MFMA16(wb[t][kk], xa[sp][kk], acc[t])   // W in A slot -> transposed D
                                     : MFMA16(xa[sp][kk], wb[t][kk], acc[t]);  // x in A slot -> standard D

            if (m == 0) {
                // fold kexp into Q before bf16 pack (saves a mul per P elem in Phase C)
#pragma unroll
                for (int t = 0; t < 4; ++t)
#pragma unroll
                    for (int e = 0; e < 4; ++e) acc[t][e] *= kexp;
#pragma unroll
                for (int kk = 0; kk < 2; ++kk) {
                    short8 q = pack8(acc[2 * kk], acc[2 * kk + 1]);
                    if (sp) qfB[kk] = q; else qfA[kk] = q;
                }
            } else if (m == 1) {
#pragma unroll
                for (int kk = 0; kk < 2; ++kk)
                    kf_lds[((s * 2 + kk) * 4 + lg) * 16 + lr] = pack8(acc[2 * kk], acc[2 * kk + 1]);
            } else {
#pragma unroll
                for (int t = 0; t < 4; ++t)
                    vq_lds[(lg * 64 + 16 * t + lr) * 16 + (s ^ xsw)] = pack4(acc[t]);
            }
        }
    }
    __syncthreads();

    // ---------- Phase C: streaming causal attention; loads hoisted & shared (R11) ----------
    f32x4 oA[4], oB[4];
#pragma unroll
    for (int t = 0; t < 4; ++t) {
        oA[t] = (f32x4){0.f, 0.f, 0.f, 0.f};
        oB[t] = (f32x4){0.f, 0.f, 0.f, 0.f};
    }
    f32x4 smA = (f32x4){0.f, 0.f, 0.f, 0.f};
    f32x4 smB = (f32x4){0.f, 0.f, 0.f, 0.f};

#pragma unroll
    for (int kt = 0; kt < 8; ++kt) {
        const int j0 = 2 * kt, j1 = 2 * kt + 1;

        // ---- UNGUARDED shared loads (always in-bounds: kf has 16 tiles, vb slots even<=14) ----
        const short8 kf0a = kf_lds[((j0 * 2 + 0) * 4 + lg) * 16 + lr];
        const short8 kf0b = kf_lds[((j0 * 2 + 1) * 4 + lg) * 16 + lr];
        const short8 kf1a = kf_lds[((j1 * 2 + 0) * 4 + lg) * 16 + lr];
        const short8 kf1b = kf_lds[((j1 * 2 + 1) * 4 + lg) * 16 + lr];
        const short8 vb0 = *(const short8*)&vq_lds[(lg * 64 +  0 + lr) * 16 + (j0 ^ xsw)];
        const short8 vb1 = *(const short8*)&vq_lds[(lg * 64 + 16 + lr) * 16 + (j0 ^ xsw)];
        const short8 vb2 = *(const short8*)&vq_lds[(lg * 64 + 32 + lr) * 16 + (j0 ^ xsw)];
        const short8 vb3 = *(const short8*)&vq_lds[(lg * 64 + 48 + lr) * 16 + (j0 ^ xsw)];

        // ---- strip A tile-pair kt ----
        if (2 * kt < ntA) {
            f32x4 p0 = (f32x4){0.f, 0.f, 0.f, 0.f};
            f32x4 p1 = (f32x4){0.f, 0.f, 0.f, 0.f};
            p0 = MFMA16(kf0a, qfA[0], p0);
            p0 = MFMA16(kf0b, qfA[1], p0);
            const bool h1 = (j1 < ntA);
            if (h1) {
                p1 = MFMA16(kf1a, qfA[0], p1);
                p1 = MFMA16(kf1b, qfA[1], p1);
            }
#pragma unroll
            for (int e = 0; e < 4; ++e) p0[e] = __builtin_amdgcn_exp2f(p0[e]);
            if (j0 == sA) {
#pragma unroll
                for (int e = 0; e < 4; ++e) p0[e] = (4 * lg + e > lr) ? 0.f : p0[e];
            }
            if (h1) {
#pragma unroll
                for (int e = 0; e < 4; ++e) p1[e] = __builtin_amdgcn_exp2f(p1[e]);
                if (j1 == sA) {
#pragma unroll
                    for (int e = 0; e < 4; ++e) p1[e] = (4 * lg + e > lr) ? 0.f : p1[e];
                }
            }
#pragma unroll
            for (int e = 0; e < 4; ++e) smA[e] += p0[e] + p1[e];
            short8 pa = pack8(p0, p1);
            oA[0] = MFMA16(pa, vb0, oA[0]);
            oA[1] = MFMA16(pa, vb1, oA[1]);
            oA[2] = MFMA16(pa, vb2, oA[2]);
            oA[3] = MFMA16(pa, vb3, oA[3]);
        }

        // ---- strip B tile-pair kt ----
        if (2 * kt < ntB) {
            f32x4 p0 = (f32x4){0.f, 0.f, 0.f, 0.f};
            f32x4 p1 = (f32x4){0.f, 0.f, 0.f, 0.f};
            p0 = MFMA16(kf0a, qfB[0], p0);
            p0 = MFMA16(kf0b, qfB[1], p0);
            const bool h1 = (j1 < ntB);
            if (h1) {
                p1 = MFMA16(kf1a, qfB[0], p1);
                p1 = MFMA16(kf1b, qfB[1], p1);
            }
#pragma unroll
            for (int e = 0; e < 4; ++e) p0[e] = __builtin_amdgcn_exp2f(p0[e]);
            if (j0 == sB) {
#pragma unroll
                for (int e = 0; e < 4; ++e) p0[e] = (4 * lg + e > lr) ? 0.f : p0[e];
            }
            if (h1) {
#pragma unroll
                for (int e = 0; e < 4; ++e) p1[e] = __builtin_amdgcn_exp2f(p1[e]);
                if (j1 == sB) {
#pragma unroll
                    for (int e = 0; e < 4; ++e) p1[e] = (4 * lg + e > lr) ? 0.f : p1[e];
                }
            }
#pragma unroll
            for (int e = 0; e < 4; ++e) smB[e] += p0[e] + p1[e];
            short8 pa = pack8(p0, p1);
            oB[0] = MFMA16(pa, vb0, oB[0]);
            oB[1] = MFMA16(pa, vb1, oB[1]);
            oB[2] = MFMA16(pa, vb2, oB[2]);
            oB[3] = MFMA16(pa, vb3, oB[3]);
        }
    }
    float fA = (smA[0] + smA[1]) + (smA[2] + smA[3]);
    fA += __shfl_xor(fA, 16);
    fA += __shfl_xor(fA, 32);
    float fB = (smB[0] + smB[1]) + (smB[2] + smB[3]);
    fB += __shfl_xor(fB, 16);
    fB += __shfl_xor(fB, 32);
    const float rvA = __builtin_amdgcn_rcpf(fA);
    const float rvB = __builtin_amdgcn_rcpf(fB);

    // ---------- Epilogue: LDS restage (kf/vq dead) -> coalesced dwordx4 stores — proven R4 ----------
    __syncthreads();
#pragma unroll
    for (int sp = 0; sp < 2; ++sp) {
        const int s = sp ? sB : sA;
        const float rv = sp ? rvB : rvA;
        float dn[4];
#pragma unroll
        for (int reg = 0; reg < 4; ++reg) dn[reg] = __shfl(rv, 4 * lg + reg);
#pragma unroll
        for (int t = 0; t < 4; ++t)
#pragma unroll
            for (int reg = 0; reg < 4; ++reg) {
                const int row = 4 * lg + reg;                    // query row within strip
                const int col = (16 * t + lr) ^ (lg << 4);       // XOR key = row>>2 = lg
                const f32x4 o = sp ? oB[t] : oA[t];
                stage[(s * 16 + row) * 64 + col] = o[reg] * dn[reg];
            }
    }
    // own-wave data only: compiler inserts the lgkmcnt wait for the ds_write->ds_read dep
#pragma unroll
    for (int sp = 0; sp < 2; ++sp) {
        const int s = sp ? sB : sA;
#pragma unroll
        for (int i = 0; i < 4; ++i) {
            const int row = 4 * i + lg;
            const int col = (4 * lr) ^ (i << 4);                 // XOR key = row>>2 = i
            f32x4 vv = *(const f32x4*)&stage[(s * 16 + row) * 64 + col];
            *(f32x4*)&out[((size_t)b * TB + 16 * s + row) * HH + 4 * lr] = vv;
        }
    }
}

extern "C" void kernel_launch(void* const* d_in, const int* in_sizes, int n_in,
                              void* d_out, int out_size, void* d_ws, size_t ws_size,
                              hipStream_t stream) {
    const float* x  = (const float*)d_in[0];
    const float* Wq = (const float*)d_in[1];
    const float* Wk = (const float*)d_in[2];
    const float* Wv = (const float*)d_in[3];
    float* out = (float*)d_out;
    const int Bn = in_sizes[0] / (TB * CC);   // 2048
    if (ws_size >= 3 * 4 * 2 * 64 * sizeof(short8)) {
        short8* wf = (short8*)d_ws;
        pack_w<<<1, 512, 0, stream>>>(Wq, Wk, Wv, wf);
        attn_fused<true><<<Bn, 512, 0, stream>>>(x, Wq, Wk, Wv, wf, out);
    } else {
        attn_fused<false><<<Bn, 512, 0, stream>>>(x, Wq, Wk, Wv, nullptr, out);
    }
}